// Round 14
// baseline (248.579 us; speedup 1.0000x reference)
//
#include <hip/hip_runtime.h>
#include <hip/hip_bf16.h>
#include <cstdint>

#define N_NODES 100000
#define N_EDGES 1600000
#define DIM 128
#define K2 256
#define ODIM 64
#define NPB 64
#define CB 98            // coarse buckets: dst>>10 (1024 nodes each)
#define NREP 8           // replicas (one per XCD via blockIdx&7 heuristic)
#define CAP1 2560        // per (rep,bucket) capacity: mean ~2048, +11 sigma
#define EPB 4096         // edges per k_bucket block
#define NWAVE 16         // waves per k_bucket block

typedef __hip_bfloat16 bf16;
typedef __attribute__((ext_vector_type(8))) short bfrag;   // 8 bf16 = 4 VGPRs
typedef __attribute__((ext_vector_type(4))) float f32x4;
typedef __attribute__((ext_vector_type(2))) float f32x2;

__device__ __forceinline__ void gload16(const void* g, void* l) {
  __builtin_amdgcn_global_load_lds((const __attribute__((address_space(1))) void*)g,
                                   (__attribute__((address_space(3))) void*)l, 16, 0, 0);
}

// ---------------- bucket binning: per-wave hist + LDS-sort, bulk-append ----------------
__global__ __launch_bounds__(1024) void k_bucket(const int* __restrict__ src,
                                                 const int* __restrict__ dst,
                                                 int* __restrict__ gcur,
                                                 uint32_t* __restrict__ bdata) {
  __shared__ int wh[NWAVE][CB];    // per-wave counts -> per-wave start offsets
  __shared__ int wcur[NWAVE][CB];  // per-wave cursors
  __shared__ int hist[CB], hbase[CB], gstart[CB];
  __shared__ uint32_t ent[EPB];
  __shared__ uint8_t kslot[EPB];
  const int tid = threadIdx.x;
  const int wave = tid >> 6;
  const int rep = blockIdx.x & (NREP - 1);
  const int e0 = blockIdx.x * EPB;
  const int cnt = min(EPB, N_EDGES - e0);

  for (int i = tid; i < NWAVE * CB; i += 1024) {
    ((int*)wh)[i] = 0;
    ((int*)wcur)[i] = 0;
  }
  __syncthreads();

  const int me0 = e0 + tid * 4;
  int ss[4], dd[4];
  int nmine = max(0, min(4, N_EDGES - me0));
  if (nmine == 4) {
    *(int4*)ss = *(const int4*)(src + me0);
    *(int4*)dd = *(const int4*)(dst + me0);
  } else {
    for (int q = 0; q < nmine; ++q) { ss[q] = src[me0 + q]; dd[q] = dst[me0 + q]; }
  }

#pragma unroll
  for (int q = 0; q < 4; ++q)
    if (q < nmine) atomicAdd(&wh[wave][dd[q] >> 10], 1);
  __syncthreads();

  if (tid < CB) {
    int run = 0;
#pragma unroll
    for (int w = 0; w < NWAVE; ++w) {
      int c = wh[w][tid];
      wh[w][tid] = run;
      run += c;
    }
    hist[tid] = run;
  }
  __syncthreads();

  if (tid == 0) {
    int run = 0;
    for (int b = 0; b < CB; ++b) { hbase[b] = run; run += hist[b]; }
  }
  __syncthreads();

#pragma unroll
  for (int q = 0; q < 4; ++q)
    if (q < nmine) {
      int key = dd[q] >> 10;
      int r = atomicAdd(&wcur[wave][key], 1);
      int p = hbase[key] + wh[wave][key] + r;
      ent[p] = ((uint32_t)ss[q] << 10) | (uint32_t)(dd[q] & 1023);
      kslot[p] = (uint8_t)key;
    }
  __syncthreads();

  if (tid < CB && hist[tid] > 0)
    gstart[tid] = atomicAdd(&gcur[rep * CB + tid], hist[tid]);
  __syncthreads();

  for (int i = tid; i < cnt; i += 1024) {
    int k = kslot[i];
    int pos = gstart[k] + (i - hbase[k]);
    if (pos < CAP1)
      bdata[((size_t)(rep * CB + k)) * CAP1 + pos] = ent[i];
  }
}

// ---------------- per-coarse-bucket CSR: 1024-node hist + scan + rank scatter ----------------
// col[] stores BYTE offsets (src * 128, fp8 rows) for the gather kernel.
__global__ __launch_bounds__(256) void k_csr(const uint32_t* __restrict__ bdata,
                                             const int* __restrict__ gcur,
                                             int* __restrict__ rowptr,
                                             int* __restrict__ col) {
  __shared__ int nc[1024], noff[1024];
  __shared__ int red[256];
  __shared__ int sz[NREP];
  const int b = blockIdx.x, tid = threadIdx.x;

  if (tid < NREP) sz[tid] = min(gcur[tid * CB + b], CAP1);

  int part = 0;
  for (int i = tid; i < NREP * b; i += 256) {
    int bp = i >> 3, r = i & 7;
    part += min(gcur[r * CB + bp], CAP1);
  }
  red[tid] = part;
  __syncthreads();
  for (int off = 128; off > 0; off >>= 1) {
    if (tid < off) red[tid] += red[tid + off];
    __syncthreads();
  }
  const int base = red[0];
  __syncthreads();

  for (int i = tid; i < 1024; i += 256) nc[i] = 0;
  __syncthreads();

  for (int r = 0; r < NREP; ++r) {
    int c = sz[r];
    const uint32_t* seg = bdata + ((size_t)(r * CB + b)) * CAP1;
    for (int i = tid; i < c; i += 256)
      atomicAdd(&nc[seg[i] & 1023], 1);
  }
  __syncthreads();

  int loc[4], s = 0;
#pragma unroll
  for (int q = 0; q < 4; ++q) { loc[q] = nc[tid * 4 + q]; s += loc[q]; }
  red[tid] = s;
  __syncthreads();
  for (int off = 1; off < 256; off <<= 1) {
    int add = (tid >= off) ? red[tid - off] : 0;
    __syncthreads();
    red[tid] += add;
    __syncthreads();
  }
  int p = red[tid] - s;
#pragma unroll
  for (int q = 0; q < 4; ++q) { noff[tid * 4 + q] = p; p += loc[q]; }
  __syncthreads();

  for (int i = tid; i < 1024; i += 256) {
    int n = b * 1024 + i;
    if (n < N_NODES) rowptr[n] = base + noff[i];
  }
  if (b == 0 && tid == 0) rowptr[N_NODES] = N_EDGES;

  for (int i = tid; i < 1024; i += 256) nc[i] = 0;
  __syncthreads();

  for (int r = 0; r < NREP; ++r) {
    int c = sz[r];
    const uint32_t* seg = bdata + ((size_t)(r * CB + b)) * CAP1;
    for (int i = tid; i < c; i += 256) {
      uint32_t e = seg[i];
      int n = e & 1023;
      int pos = atomicAdd(&nc[n], 1);
      col[base + noff[n] + pos] = (int)((e >> 10) << 7);   // byte offset: src * 128 (fp8)
    }
  }
}

// ---------------- precompute: x -> bf16 + fp8 (8 floats/thread) ----------------
__global__ __launch_bounds__(256) void k_cvt(const float* __restrict__ x,
                                             bf16* __restrict__ xb,
                                             uint8_t* __restrict__ x8) {
  int i = (blockIdx.x * 256 + threadIdx.x) * 8;
  if (i >= N_NODES * DIM) return;
  float4 v0 = *(const float4*)(x + i);
  float4 v1 = *(const float4*)(x + i + 4);
  bf16 t[8];
  t[0] = __float2bfloat16(v0.x); t[1] = __float2bfloat16(v0.y);
  t[2] = __float2bfloat16(v0.z); t[3] = __float2bfloat16(v0.w);
  t[4] = __float2bfloat16(v1.x); t[5] = __float2bfloat16(v1.y);
  t[6] = __float2bfloat16(v1.z); t[7] = __float2bfloat16(v1.w);
  *(uint4*)(xb + i) = *(uint4*)t;
  int lo = __builtin_amdgcn_cvt_pk_fp8_f32(v0.x, v0.y, 0, false);
  lo = __builtin_amdgcn_cvt_pk_fp8_f32(v0.z, v0.w, lo, true);
  int hi = __builtin_amdgcn_cvt_pk_fp8_f32(v1.x, v1.y, 0, false);
  hi = __builtin_amdgcn_cvt_pk_fp8_f32(v1.z, v1.w, hi, true);
  uint2 o; o.x = (uint32_t)lo; o.y = (uint32_t)hi;
  *(uint2*)(x8 + i) = o;
}

// ---------------- precompute: pack weights transposed bf16 ----------------
__global__ __launch_bounds__(256) void k_prepw(const float* __restrict__ wl0,
                                               const float* __restrict__ wr0,
                                               const float* __restrict__ wl1,
                                               const float* __restrict__ wr1,
                                               const float* __restrict__ wo,
                                               bf16* __restrict__ WT0,
                                               bf16* __restrict__ WT1,
                                               bf16* __restrict__ WoT) {
  int g = blockIdx.x * 256 + threadIdx.x;
  if (g < 32768) {
    int j = g >> 8, k = g & 255;
    float v = (k < DIM) ? wl0[k * DIM + j] : wr0[(k - DIM) * DIM + j];
    WT0[g] = __float2bfloat16(v);
  } else if (g < 65536) {
    int gg = g - 32768;
    int j = gg >> 8, k = gg & 255;
    float v = (k < DIM) ? wl1[k * DIM + j] : wr1[(k - DIM) * DIM + j];
    WT1[gg] = __float2bfloat16(v);
  } else if (g < 65536 + 8192) {
    int gg = g - 65536;
    int j = gg >> 7, k = gg & 127;
    WoT[gg] = __float2bfloat16(wo[k * ODIM + j]);
  }
}

// ---------------- pull aggregation (fp8 rows, 128B): 8 lanes x 16B per edge, 8 edges/instr ----------------
__device__ __forceinline__ void accv16(f32x2* acc, uint4 v) {
  uint32_t ws[4] = {v.x, v.y, v.z, v.w};
#pragma unroll
  for (int q = 0; q < 4; ++q) {
    acc[2 * q]     += __builtin_amdgcn_cvt_pk_f32_fp8(ws[q], false);
    acc[2 * q + 1] += __builtin_amdgcn_cvt_pk_f32_fp8(ws[q], true);
  }
}

__global__ __launch_bounds__(256) void k_agg(const uint8_t* __restrict__ feat8,
                                             const int* __restrict__ rowptr,
                                             const int* __restrict__ colb,
                                             bf16* __restrict__ agg) {
  int gid = blockIdx.x * 256 + threadIdx.x;
  int node = gid >> 6;
  if (node >= N_NODES) return;
  int lane = gid & 63;
  int g = lane >> 3, lg = lane & 7;       // 8 edge-groups x 8 lanes; lg = 16B chunk
  int beg = rowptr[node], end = rowptr[node + 1];
  const char* fb = (const char*)feat8 + lg * 16;

  f32x2 acc[8];                           // 16 features per lane
#pragma unroll
  for (int q = 0; q < 8; ++q) acc[q] = (f32x2){0.f, 0.f};

  int j = beg;
  // 16 edges in flight (2 x 8-edge groups)
  for (; j + 16 <= end; j += 16) {
    int o0 = colb[j + g];
    int o1 = colb[j + 8 + g];
    uint4 v0 = *(const uint4*)(fb + o0);
    uint4 v1 = *(const uint4*)(fb + o1);
    accv16(acc, v0);
    accv16(acc, v1);
  }
  if (j + 8 <= end) {
    int o = colb[j + g];
    uint4 v = *(const uint4*)(fb + o);
    accv16(acc, v);
    j += 8;
  }
  int rem = end - j;
  if (g < rem) {
    int o = colb[j + g];
    uint4 v = *(const uint4*)(fb + o);
    accv16(acc, v);
  }

  // reduce across the 8 edge groups (xor 8, 16, 32)
#pragma unroll
  for (int q = 0; q < 8; ++q) {
#pragma unroll
    for (int c = 0; c < 2; ++c) {
      acc[q][c] += __shfl_xor(acc[q][c], 8, 64);
      acc[q][c] += __shfl_xor(acc[q][c], 16, 64);
      acc[q][c] += __shfl_xor(acc[q][c], 32, 64);
    }
  }

  if (g == 0) {
    float inv = (end > beg) ? 1.0f / (float)(end - beg) : 0.f;
    union { uint32_t u[8]; uint4 v[2]; } o;
#pragma unroll
    for (int q = 0; q < 8; ++q) {
      __hip_bfloat162 h;
      h.x = __float2bfloat16(acc[q][0] * inv);
      h.y = __float2bfloat16(acc[q][1] * inv);
      o.u[q] = *(uint32_t*)&h;
    }
    bf16* dst = agg + (size_t)node * DIM + lg * 16;
    *(uint4*)dst = o.v[0];
    *(uint4*)(dst + 8) = o.v[1];
  }
}

// ---------------- MFMA SAGE layer: h = relu([agg|x] @ WT^T + b), writes bf16 + fp8 ----------------
__global__ __launch_bounds__(256) void k_sage(const bf16* __restrict__ agg,
                                              const bf16* __restrict__ xb,
                                              const bf16* __restrict__ WT,
                                              const float* __restrict__ bias,
                                              bf16* __restrict__ hout,
                                              uint8_t* __restrict__ h8) {
  __shared__ char sA[NPB * 512];   // 32 KB
  const int tid = threadIdx.x;
  const int base = blockIdx.x * NPB;

#pragma unroll
  for (int i = 0; i < 8; ++i) {
    int c = tid + 256 * i;
    int row = c >> 5;
    int n = min(base + row, N_NODES - 1);
    int kcg = (c & 31) ^ (row & 7);
    const bf16* sp = (kcg < 16) ? (agg + (size_t)n * DIM + kcg * 8)
                                : (xb + (size_t)n * DIM + (kcg - 16) * 8);
    gload16(sp, sA + c * 16);
  }
  __syncthreads();

  const int w = tid >> 6, lane = tid & 63;
  const int j0 = w * 32;
  const int lrow = lane & 15, lk = lane >> 4;

  f32x4 acc[4][2];
#pragma unroll
  for (int mi = 0; mi < 4; ++mi)
#pragma unroll
    for (int ni = 0; ni < 2; ++ni)
      acc[mi][ni] = (f32x4){0.f, 0.f, 0.f, 0.f};

  for (int kt = 0; kt < 8; ++kt) {
    bfrag b0 = *(const bfrag*)(WT + (size_t)(j0 + lrow) * K2 + kt * 32 + lk * 8);
    bfrag b1 = *(const bfrag*)(WT + (size_t)(j0 + 16 + lrow) * K2 + kt * 32 + lk * 8);
#pragma unroll
    for (int mi = 0; mi < 4; ++mi) {
      int row = mi * 16 + lrow;
      int byte = (row * 512 + kt * 64 + lk * 16) ^ ((row & 7) << 4);
      bfrag a = *(const bfrag*)(sA + byte);
      acc[mi][0] = __builtin_amdgcn_mfma_f32_16x16x32_bf16(a, b0, acc[mi][0], 0, 0, 0);
      acc[mi][1] = __builtin_amdgcn_mfma_f32_16x16x32_bf16(a, b1, acc[mi][1], 0, 0, 0);
    }
  }

#pragma unroll
  for (int ni = 0; ni < 2; ++ni) {
    int colj = j0 + ni * 16 + lrow;
    float bv = bias[colj];
#pragma unroll
    for (int mi = 0; mi < 4; ++mi) {
#pragma unroll
      for (int r = 0; r < 4; ++r) {
        int n = base + mi * 16 + lk * 4 + r;
        if (n < N_NODES) {
          float v = fmaxf(acc[mi][ni][r] + bv, 0.f);
          hout[(size_t)n * DIM + colj] = __float2bfloat16(v);
          h8[(size_t)n * DIM + colj] =
              (uint8_t)(__builtin_amdgcn_cvt_pk_fp8_f32(v, v, 0, false) & 0xFF);
        }
      }
    }
  }
}

// ---------------- MFMA layer 1 + head ----------------
__global__ __launch_bounds__(256) void k_out(const bf16* __restrict__ agg,
                                             const bf16* __restrict__ xb,
                                             const bf16* __restrict__ WT,
                                             const float* __restrict__ bias,
                                             const bf16* __restrict__ WoT,
                                             const float* __restrict__ bo,
                                             float* __restrict__ out) {
  __shared__ char sA[NPB * 512];
  const int tid = threadIdx.x;
  const int base = blockIdx.x * NPB;

#pragma unroll
  for (int i = 0; i < 8; ++i) {
    int c = tid + 256 * i;
    int row = c >> 5;
    int n = min(base + row, N_NODES - 1);
    int kcg = (c & 31) ^ (row & 7);
    const bf16* sp = (kcg < 16) ? (agg + (size_t)n * DIM + kcg * 8)
                                : (xb + (size_t)n * DIM + (kcg - 16) * 8);
    gload16(sp, sA + c * 16);
  }
  __syncthreads();

  const int w = tid >> 6, lane = tid & 63;
  const int j0 = w * 32;
  const int lrow = lane & 15, lk = lane >> 4;

  f32x4 acc[4][2];
#pragma unroll
  for (int mi = 0; mi < 4; ++mi)
#pragma unroll
    for (int ni = 0; ni < 2; ++ni)
      acc[mi][ni] = (f32x4){0.f, 0.f, 0.f, 0.f};

  for (int kt = 0; kt < 8; ++kt) {
    bfrag b0 = *(const bfrag*)(WT + (size_t)(j0 + lrow) * K2 + kt * 32 + lk * 8);
    bfrag b1 = *(const bfrag*)(WT + (size_t)(j0 + 16 + lrow) * K2 + kt * 32 + lk * 8);
#pragma unroll
    for (int mi = 0; mi < 4; ++mi) {
      int row = mi * 16 + lrow;
      int byte = (row * 512 + kt * 64 + lk * 16) ^ ((row & 7) << 4);
      bfrag a = *(const bfrag*)(sA + byte);
      acc[mi][0] = __builtin_amdgcn_mfma_f32_16x16x32_bf16(a, b0, acc[mi][0], 0, 0, 0);
      acc[mi][1] = __builtin_amdgcn_mfma_f32_16x16x32_bf16(a, b1, acc[mi][1], 0, 0, 0);
    }
  }

  __syncthreads();   // reuse sA as h1 tile [64 rows][256B], swizzled (ds_write path)
#pragma unroll
  for (int ni = 0; ni < 2; ++ni) {
    int colj = j0 + ni * 16 + lrow;
    float bv = bias[colj];
#pragma unroll
    for (int mi = 0; mi < 4; ++mi) {
#pragma unroll
      for (int r = 0; r < 4; ++r) {
        int row = mi * 16 + lk * 4 + r;
        float v = fmaxf(acc[mi][ni][r] + bv, 0.f);
        int byte = (row * 256 + colj * 2) ^ ((row & 7) << 4);
        *(bf16*)(sA + byte) = __float2bfloat16(v);
      }
    }
  }
  __syncthreads();

  const int jo = w * 16;
  f32x4 acc2[4];
#pragma unroll
  for (int mi = 0; mi < 4; ++mi) acc2[mi] = (f32x4){0.f, 0.f, 0.f, 0.f};

#pragma unroll
  for (int kt = 0; kt < 4; ++kt) {
    bfrag b = *(const bfrag*)(WoT + (size_t)(jo + lrow) * DIM + kt * 32 + lk * 8);
#pragma unroll
    for (int mi = 0; mi < 4; ++mi) {
      int row = mi * 16 + lrow;
      int byte = (row * 256 + kt * 64 + lk * 16) ^ ((row & 7) << 4);
      bfrag a = *(const bfrag*)(sA + byte);
      acc2[mi] = __builtin_amdgcn_mfma_f32_16x16x32_bf16(a, b, acc2[mi], 0, 0, 0);
    }
  }

  int colj = jo + lrow;
  float bv = bo[colj];
#pragma unroll
  for (int mi = 0; mi < 4; ++mi) {
#pragma unroll
    for (int r = 0; r < 4; ++r) {
      int n = base + mi * 16 + lk * 4 + r;
      if (n < N_NODES)
        out[(size_t)n * ODIM + colj] = 1.f / (1.f + __expf(-(acc2[mi][r] + bv)));
    }
  }
}

extern "C" void kernel_launch(void* const* d_in, const int* in_sizes, int n_in,
                              void* d_out, int out_size, void* d_ws, size_t ws_size,
                              hipStream_t stream) {
  const float* x     = (const float*)d_in[0];
  const int*   ei    = (const int*)d_in[1];
  const float* w_l0  = (const float*)d_in[2];
  const float* b_l0  = (const float*)d_in[3];
  const float* w_r0  = (const float*)d_in[4];
  const float* w_l1  = (const float*)d_in[5];
  const float* b_l1  = (const float*)d_in[6];
  const float* w_r1  = (const float*)d_in[7];
  const float* w_out = (const float*)d_in[8];
  const float* b_out = (const float*)d_in[9];
  float* out = (float*)d_out;

  const int* src = ei;
  const int* dst = ei + N_EDGES;

  char* ws = (char*)d_ws;
  int*      rowptr = (int*)(ws);                          // 400,004 B
  int*      gcur   = (int*)(ws + (512u << 10));           // 3,136 B
  int*      col    = (int*)(ws + (1u << 20));             // 6.4 MB (byte offsets)
  uint32_t* bdata  = (uint32_t*)(ws + (8u << 20));        // 8.03 MB (dead after k_csr)
  uint8_t*  x8     = (uint8_t*)(ws + (8u << 20));         // 12.8 MB (overlays bdata)
  uint8_t*  h08    = (uint8_t*)(ws + (8u << 20));         // 12.8 MB (overlays x8 after layer-0 agg)
  bf16*     WT0    = (bf16*)(ws + (21u << 20));           // 64 KB
  bf16*     WT1    = (bf16*)(ws + (21u << 20) + 65536);   // 64 KB
  bf16*     WoT    = (bf16*)(ws + (21u << 20) + 131072);  // 16 KB
  bf16*     aggb   = (bf16*)(ws + (22ull << 20));         // 25.6 MB
  bf16*     h0b    = (bf16*)(ws + (48ull << 20));         // 25.6 MB
  bf16*     xb     = (bf16*)(ws + (74ull << 20));         // 25.6 MB (~99.6 MB total)

  // --- CSR build first (bdata region is then reused for fp8 tables) ---
  hipMemsetAsync(gcur, 0, NREP * CB * sizeof(int), stream);
  k_bucket<<<(N_EDGES + EPB - 1) / EPB, 1024, 0, stream>>>(src, dst, gcur, bdata);
  k_csr   <<<CB, 256, 0, stream>>>(bdata, gcur, rowptr, col);

  // --- precompute (x -> bf16 + fp8; weights) ---
  k_cvt  <<<(N_NODES * DIM / 8 + 255) / 256, 256, 0, stream>>>(x, xb, x8);
  k_prepw<<<(65536 + 8192 + 255) / 256, 256, 0, stream>>>(w_l0, w_r0, w_l1, w_r1, w_out,
                                                          WT0, WT1, WoT);

  const int ablocks = (N_NODES * 64 + 255) / 256;
  const int gblocks = (N_NODES + NPB - 1) / NPB;

  // --- layer 0 ---
  k_agg <<<ablocks, 256, 0, stream>>>(x8, rowptr, col, aggb);
  k_sage<<<gblocks, 256, 0, stream>>>(aggb, xb, WT0, b_l0, h0b, h08);

  // --- layer 1 + head ---
  k_agg<<<ablocks, 256, 0, stream>>>(h08, rowptr, col, aggb);
  k_out<<<gblocks, 256, 0, stream>>>(aggb, h0b, WT1, b_l1, WoT, b_out, out);
}

// Round 15
// 233.235 us; speedup vs baseline: 1.0658x; 1.0658x over previous
//
#include <hip/hip_runtime.h>
#include <hip/hip_bf16.h>
#include <cstdint>

#define N_NODES 100000
#define N_EDGES 1600000
#define DIM 128
#define K2 256
#define ODIM 64
#define NPB 64
#define CB 98            // coarse buckets: dst>>10 (1024 nodes each)
#define NREP 8           // replicas (one per XCD via blockIdx&7 heuristic)
#define CAP1 2560        // per (rep,bucket) capacity: mean ~2048, +11 sigma
#define EPB 4096         // edges per k_bucket block
#define NWAVE 16         // waves per k_bucket block

typedef __hip_bfloat16 bf16;
typedef __attribute__((ext_vector_type(8))) short bfrag;   // 8 bf16 = 4 VGPRs
typedef __attribute__((ext_vector_type(4))) float f32x4;
typedef __attribute__((ext_vector_type(2))) float f32x2;

__device__ __forceinline__ void gload16(const void* g, void* l) {
  __builtin_amdgcn_global_load_lds((const __attribute__((address_space(1))) void*)g,
                                   (__attribute__((address_space(3))) void*)l, 16, 0, 0);
}

// ---------------- bucket binning: per-wave hist + LDS-sort, bulk-append ----------------
__global__ __launch_bounds__(1024) void k_bucket(const int* __restrict__ src,
                                                 const int* __restrict__ dst,
                                                 int* __restrict__ gcur,
                                                 uint32_t* __restrict__ bdata) {
  __shared__ int wh[NWAVE][CB];    // per-wave counts -> per-wave start offsets
  __shared__ int wcur[NWAVE][CB];  // per-wave cursors
  __shared__ int hist[CB], hbase[CB], gstart[CB];
  __shared__ uint32_t ent[EPB];
  __shared__ uint8_t kslot[EPB];
  const int tid = threadIdx.x;
  const int wave = tid >> 6;
  const int rep = blockIdx.x & (NREP - 1);
  const int e0 = blockIdx.x * EPB;
  const int cnt = min(EPB, N_EDGES - e0);

  for (int i = tid; i < NWAVE * CB; i += 1024) {
    ((int*)wh)[i] = 0;
    ((int*)wcur)[i] = 0;
  }
  __syncthreads();

  const int me0 = e0 + tid * 4;
  int ss[4], dd[4];
  int nmine = max(0, min(4, N_EDGES - me0));
  if (nmine == 4) {
    *(int4*)ss = *(const int4*)(src + me0);
    *(int4*)dd = *(const int4*)(dst + me0);
  } else {
    for (int q = 0; q < nmine; ++q) { ss[q] = src[me0 + q]; dd[q] = dst[me0 + q]; }
  }

#pragma unroll
  for (int q = 0; q < 4; ++q)
    if (q < nmine) atomicAdd(&wh[wave][dd[q] >> 10], 1);
  __syncthreads();

  // per-bucket: totals + per-wave start offsets (wh[w][b] becomes wave w's offset)
  if (tid < CB) {
    int run = 0;
#pragma unroll
    for (int w = 0; w < NWAVE; ++w) {
      int c = wh[w][tid];
      wh[w][tid] = run;
      run += c;
    }
    hist[tid] = run;
  }
  __syncthreads();

  if (tid == 0) {
    int run = 0;
    for (int b = 0; b < CB; ++b) { hbase[b] = run; run += hist[b]; }
  }
  __syncthreads();

#pragma unroll
  for (int q = 0; q < 4; ++q)
    if (q < nmine) {
      int key = dd[q] >> 10;
      int r = atomicAdd(&wcur[wave][key], 1);
      int p = hbase[key] + wh[wave][key] + r;
      ent[p] = ((uint32_t)ss[q] << 10) | (uint32_t)(dd[q] & 1023);
      kslot[p] = (uint8_t)key;
    }
  __syncthreads();

  if (tid < CB && hist[tid] > 0)
    gstart[tid] = atomicAdd(&gcur[rep * CB + tid], hist[tid]);
  __syncthreads();

  for (int i = tid; i < cnt; i += 1024) {
    int k = kslot[i];
    int pos = gstart[k] + (i - hbase[k]);
    if (pos < CAP1)
      bdata[((size_t)(rep * CB + k)) * CAP1 + pos] = ent[i];
  }
}

// ---------------- per-coarse-bucket CSR: 1024-node hist + scan + rank scatter ----------------
// col[] stores BYTE offsets (src * 128, fp8 rows) for the gather kernel.
__global__ __launch_bounds__(256) void k_csr(const uint32_t* __restrict__ bdata,
                                             const int* __restrict__ gcur,
                                             int* __restrict__ rowptr,
                                             int* __restrict__ col) {
  __shared__ int nc[1024], noff[1024];
  __shared__ int red[256];
  __shared__ int sz[NREP];
  const int b = blockIdx.x, tid = threadIdx.x;

  if (tid < NREP) sz[tid] = min(gcur[tid * CB + b], CAP1);

  int part = 0;
  for (int i = tid; i < NREP * b; i += 256) {
    int bp = i >> 3, r = i & 7;
    part += min(gcur[r * CB + bp], CAP1);
  }
  red[tid] = part;
  __syncthreads();
  for (int off = 128; off > 0; off >>= 1) {
    if (tid < off) red[tid] += red[tid + off];
    __syncthreads();
  }
  const int base = red[0];
  __syncthreads();

  for (int i = tid; i < 1024; i += 256) nc[i] = 0;
  __syncthreads();

  for (int r = 0; r < NREP; ++r) {
    int c = sz[r];
    const uint32_t* seg = bdata + ((size_t)(r * CB + b)) * CAP1;
    for (int i = tid; i < c; i += 256)
      atomicAdd(&nc[seg[i] & 1023], 1);
  }
  __syncthreads();

  int loc[4], s = 0;
#pragma unroll
  for (int q = 0; q < 4; ++q) { loc[q] = nc[tid * 4 + q]; s += loc[q]; }
  red[tid] = s;
  __syncthreads();
  for (int off = 1; off < 256; off <<= 1) {
    int add = (tid >= off) ? red[tid - off] : 0;
    __syncthreads();
    red[tid] += add;
    __syncthreads();
  }
  int p = red[tid] - s;
#pragma unroll
  for (int q = 0; q < 4; ++q) { noff[tid * 4 + q] = p; p += loc[q]; }
  __syncthreads();

  for (int i = tid; i < 1024; i += 256) {
    int n = b * 1024 + i;
    if (n < N_NODES) rowptr[n] = base + noff[i];
  }
  if (b == 0 && tid == 0) rowptr[N_NODES] = N_EDGES;

  for (int i = tid; i < 1024; i += 256) nc[i] = 0;
  __syncthreads();

  for (int r = 0; r < NREP; ++r) {
    int c = sz[r];
    const uint32_t* seg = bdata + ((size_t)(r * CB + b)) * CAP1;
    for (int i = tid; i < c; i += 256) {
      uint32_t e = seg[i];
      int n = e & 1023;
      int pos = atomicAdd(&nc[n], 1);
      col[base + noff[n] + pos] = (int)((e >> 10) << 7);   // byte offset: src * 128 (fp8)
    }
  }
}

// ---------------- precompute: x -> bf16 + fp8 (8 floats/thread) ----------------
__global__ __launch_bounds__(256) void k_cvt(const float* __restrict__ x,
                                             bf16* __restrict__ xb,
                                             uint8_t* __restrict__ x8) {
  int i = (blockIdx.x * 256 + threadIdx.x) * 8;
  if (i >= N_NODES * DIM) return;
  float4 v0 = *(const float4*)(x + i);
  float4 v1 = *(const float4*)(x + i + 4);
  bf16 t[8];
  t[0] = __float2bfloat16(v0.x); t[1] = __float2bfloat16(v0.y);
  t[2] = __float2bfloat16(v0.z); t[3] = __float2bfloat16(v0.w);
  t[4] = __float2bfloat16(v1.x); t[5] = __float2bfloat16(v1.y);
  t[6] = __float2bfloat16(v1.z); t[7] = __float2bfloat16(v1.w);
  *(uint4*)(xb + i) = *(uint4*)t;
  int lo = __builtin_amdgcn_cvt_pk_fp8_f32(v0.x, v0.y, 0, false);
  lo = __builtin_amdgcn_cvt_pk_fp8_f32(v0.z, v0.w, lo, true);
  int hi = __builtin_amdgcn_cvt_pk_fp8_f32(v1.x, v1.y, 0, false);
  hi = __builtin_amdgcn_cvt_pk_fp8_f32(v1.z, v1.w, hi, true);
  uint2 o; o.x = (uint32_t)lo; o.y = (uint32_t)hi;
  *(uint2*)(x8 + i) = o;
}

// ---------------- precompute: pack weights transposed bf16 ----------------
__global__ __launch_bounds__(256) void k_prepw(const float* __restrict__ wl0,
                                               const float* __restrict__ wr0,
                                               const float* __restrict__ wl1,
                                               const float* __restrict__ wr1,
                                               const float* __restrict__ wo,
                                               bf16* __restrict__ WT0,
                                               bf16* __restrict__ WT1,
                                               bf16* __restrict__ WoT) {
  int g = blockIdx.x * 256 + threadIdx.x;
  if (g < 32768) {
    int j = g >> 8, k = g & 255;
    float v = (k < DIM) ? wl0[k * DIM + j] : wr0[(k - DIM) * DIM + j];
    WT0[g] = __float2bfloat16(v);
  } else if (g < 65536) {
    int gg = g - 32768;
    int j = gg >> 8, k = gg & 255;
    float v = (k < DIM) ? wl1[k * DIM + j] : wr1[(k - DIM) * DIM + j];
    WT1[gg] = __float2bfloat16(v);
  } else if (g < 65536 + 8192) {
    int gg = g - 65536;
    int j = gg >> 7, k = gg & 127;
    WoT[gg] = __float2bfloat16(wo[k * ODIM + j]);
  }
}

// ---------------- pull aggregation (fp8 rows, 128B): 1 wave/node, 16 edges in flight ----------------
__device__ __forceinline__ void accv8(f32x2* acc, uint2 v) {
  f32x2 t0 = __builtin_amdgcn_cvt_pk_f32_fp8(v.x, false);
  f32x2 t1 = __builtin_amdgcn_cvt_pk_f32_fp8(v.x, true);
  f32x2 t2 = __builtin_amdgcn_cvt_pk_f32_fp8(v.y, false);
  f32x2 t3 = __builtin_amdgcn_cvt_pk_f32_fp8(v.y, true);
  acc[0] += t0; acc[1] += t1; acc[2] += t2; acc[3] += t3;
}

__global__ __launch_bounds__(256) void k_agg(const uint8_t* __restrict__ feat8,
                                             const int* __restrict__ rowptr,
                                             const int* __restrict__ colb,
                                             bf16* __restrict__ agg) {
  int gid = blockIdx.x * 256 + threadIdx.x;
  int node = gid >> 6;
  if (node >= N_NODES) return;
  int lane = gid & 63;
  int g = lane >> 4, lg = lane & 15;
  int beg = rowptr[node], end = rowptr[node + 1];
  const char* fb = (const char*)feat8 + lg * 8;

  f32x2 acc[4];
#pragma unroll
  for (int q = 0; q < 4; ++q) acc[q] = (f32x2){0.f, 0.f};

  int j = beg;
  for (; j + 16 <= end; j += 16) {
    int o0 = colb[j + g];
    int o1 = colb[j + 4 + g];
    int o2 = colb[j + 8 + g];
    int o3 = colb[j + 12 + g];
    uint2 v0 = *(const uint2*)(fb + o0);
    uint2 v1 = *(const uint2*)(fb + o1);
    uint2 v2 = *(const uint2*)(fb + o2);
    uint2 v3 = *(const uint2*)(fb + o3);
    accv8(acc, v0); accv8(acc, v1); accv8(acc, v2); accv8(acc, v3);
  }
  for (; j + 4 <= end; j += 4) {
    int o = colb[j + g];
    uint2 v = *(const uint2*)(fb + o);
    accv8(acc, v);
  }
  int rem = end - j;
  if (g < rem) {
    int o = colb[j + g];
    uint2 v = *(const uint2*)(fb + o);
    accv8(acc, v);
  }

#pragma unroll
  for (int q = 0; q < 4; ++q) {
#pragma unroll
    for (int c = 0; c < 2; ++c) {
      acc[q][c] += __shfl_xor(acc[q][c], 16, 64);
      acc[q][c] += __shfl_xor(acc[q][c], 32, 64);
    }
  }

  if (g == 0) {
    float inv = (end > beg) ? 1.0f / (float)(end - beg) : 0.f;
    union { uint32_t u[4]; uint4 v; } o;
#pragma unroll
    for (int q = 0; q < 4; ++q) {
      __hip_bfloat162 h;
      h.x = __float2bfloat16(acc[q][0] * inv);
      h.y = __float2bfloat16(acc[q][1] * inv);
      o.u[q] = *(uint32_t*)&h;
    }
    *(uint4*)(agg + (size_t)node * DIM + lg * 8) = o.v;
  }
}

// ---------------- MFMA SAGE layer: h = relu([agg|x] @ WT^T + b), writes bf16 + fp8 ----------------
// A-tile staged via global_load_lds: LINEAR LDS dest, inverse-swizzled per-lane source
// (slot c holds logical chunk kc^(row&7); read path applies the same XOR -> identity).
__global__ __launch_bounds__(256) void k_sage(const bf16* __restrict__ agg,
                                              const bf16* __restrict__ xb,
                                              const bf16* __restrict__ WT,
                                              const float* __restrict__ bias,
                                              bf16* __restrict__ hout,
                                              uint8_t* __restrict__ h8) {
  __shared__ char sA[NPB * 512];   // 32 KB
  const int tid = threadIdx.x;
  const int base = blockIdx.x * NPB;

#pragma unroll
  for (int i = 0; i < 8; ++i) {
    int c = tid + 256 * i;                 // chunk 0..2047 (16B each)
    int row = c >> 5;
    int n = min(base + row, N_NODES - 1);  // clamp: garbage rows feed guarded outputs only
    int kcg = (c & 31) ^ (row & 7);        // inverse-swizzled logical chunk
    const bf16* sp = (kcg < 16) ? (agg + (size_t)n * DIM + kcg * 8)
                                : (xb + (size_t)n * DIM + (kcg - 16) * 8);
    gload16(sp, sA + c * 16);
  }
  __syncthreads();

  const int w = tid >> 6, lane = tid & 63;
  const int j0 = w * 32;
  const int lrow = lane & 15, lk = lane >> 4;

  f32x4 acc[4][2];
#pragma unroll
  for (int mi = 0; mi < 4; ++mi)
#pragma unroll
    for (int ni = 0; ni < 2; ++ni)
      acc[mi][ni] = (f32x4){0.f, 0.f, 0.f, 0.f};

  for (int kt = 0; kt < 8; ++kt) {
    bfrag b0 = *(const bfrag*)(WT + (size_t)(j0 + lrow) * K2 + kt * 32 + lk * 8);
    bfrag b1 = *(const bfrag*)(WT + (size_t)(j0 + 16 + lrow) * K2 + kt * 32 + lk * 8);
#pragma unroll
    for (int mi = 0; mi < 4; ++mi) {
      int row = mi * 16 + lrow;
      int byte = (row * 512 + kt * 64 + lk * 16) ^ ((row & 7) << 4);
      bfrag a = *(const bfrag*)(sA + byte);
      acc[mi][0] = __builtin_amdgcn_mfma_f32_16x16x32_bf16(a, b0, acc[mi][0], 0, 0, 0);
      acc[mi][1] = __builtin_amdgcn_mfma_f32_16x16x32_bf16(a, b1, acc[mi][1], 0, 0, 0);
    }
  }

#pragma unroll
  for (int ni = 0; ni < 2; ++ni) {
    int colj = j0 + ni * 16 + lrow;
    float bv = bias[colj];
#pragma unroll
    for (int mi = 0; mi < 4; ++mi) {
#pragma unroll
      for (int r = 0; r < 4; ++r) {
        int n = base + mi * 16 + lk * 4 + r;
        if (n < N_NODES) {
          float v = fmaxf(acc[mi][ni][r] + bv, 0.f);
          hout[(size_t)n * DIM + colj] = __float2bfloat16(v);
          h8[(size_t)n * DIM + colj] =
              (uint8_t)(__builtin_amdgcn_cvt_pk_fp8_f32(v, v, 0, false) & 0xFF);
        }
      }
    }
  }
}

// ---------------- MFMA layer 1 + head ----------------
__global__ __launch_bounds__(256) void k_out(const bf16* __restrict__ agg,
                                             const bf16* __restrict__ xb,
                                             const bf16* __restrict__ WT,
                                             const float* __restrict__ bias,
                                             const bf16* __restrict__ WoT,
                                             const float* __restrict__ bo,
                                             float* __restrict__ out) {
  __shared__ char sA[NPB * 512];
  const int tid = threadIdx.x;
  const int base = blockIdx.x * NPB;

#pragma unroll
  for (int i = 0; i < 8; ++i) {
    int c = tid + 256 * i;
    int row = c >> 5;
    int n = min(base + row, N_NODES - 1);
    int kcg = (c & 31) ^ (row & 7);
    const bf16* sp = (kcg < 16) ? (agg + (size_t)n * DIM + kcg * 8)
                                : (xb + (size_t)n * DIM + (kcg - 16) * 8);
    gload16(sp, sA + c * 16);
  }
  __syncthreads();

  const int w = tid >> 6, lane = tid & 63;
  const int j0 = w * 32;
  const int lrow = lane & 15, lk = lane >> 4;

  f32x4 acc[4][2];
#pragma unroll
  for (int mi = 0; mi < 4; ++mi)
#pragma unroll
    for (int ni = 0; ni < 2; ++ni)
      acc[mi][ni] = (f32x4){0.f, 0.f, 0.f, 0.f};

  for (int kt = 0; kt < 8; ++kt) {
    bfrag b0 = *(const bfrag*)(WT + (size_t)(j0 + lrow) * K2 + kt * 32 + lk * 8);
    bfrag b1 = *(const bfrag*)(WT + (size_t)(j0 + 16 + lrow) * K2 + kt * 32 + lk * 8);
#pragma unroll
    for (int mi = 0; mi < 4; ++mi) {
      int row = mi * 16 + lrow;
      int byte = (row * 512 + kt * 64 + lk * 16) ^ ((row & 7) << 4);
      bfrag a = *(const bfrag*)(sA + byte);
      acc[mi][0] = __builtin_amdgcn_mfma_f32_16x16x32_bf16(a, b0, acc[mi][0], 0, 0, 0);
      acc[mi][1] = __builtin_amdgcn_mfma_f32_16x16x32_bf16(a, b1, acc[mi][1], 0, 0, 0);
    }
  }

  __syncthreads();   // reuse sA as h1 tile [64 rows][256B], swizzled (ds_write path)
#pragma unroll
  for (int ni = 0; ni < 2; ++ni) {
    int colj = j0 + ni * 16 + lrow;
    float bv = bias[colj];
#pragma unroll
    for (int mi = 0; mi < 4; ++mi) {
#pragma unroll
      for (int r = 0; r < 4; ++r) {
        int row = mi * 16 + lk * 4 + r;
        float v = fmaxf(acc[mi][ni][r] + bv, 0.f);
        int byte = (row * 256 + colj * 2) ^ ((row & 7) << 4);
        *(bf16*)(sA + byte) = __float2bfloat16(v);
      }
    }
  }
  __syncthreads();

  const int jo = w * 16;
  f32x4 acc2[4];
#pragma unroll
  for (int mi = 0; mi < 4; ++mi) acc2[mi] = (f32x4){0.f, 0.f, 0.f, 0.f};

#pragma unroll
  for (int kt = 0; kt < 4; ++kt) {
    bfrag b = *(const bfrag*)(WoT + (size_t)(jo + lrow) * DIM + kt * 32 + lk * 8);
#pragma unroll
    for (int mi = 0; mi < 4; ++mi) {
      int row = mi * 16 + lrow;
      int byte = (row * 256 + kt * 64 + lk * 16) ^ ((row & 7) << 4);
      bfrag a = *(const bfrag*)(sA + byte);
      acc2[mi] = __builtin_amdgcn_mfma_f32_16x16x32_bf16(a, b, acc2[mi], 0, 0, 0);
    }
  }

  int colj = jo + lrow;
  float bv = bo[colj];
#pragma unroll
  for (int mi = 0; mi < 4; ++mi) {
#pragma unroll
    for (int r = 0; r < 4; ++r) {
      int n = base + mi * 16 + lk * 4 + r;
      if (n < N_NODES)
        out[(size_t)n * ODIM + colj] = 1.f / (1.f + __expf(-(acc2[mi][r] + bv)));
    }
  }
}

extern "C" void kernel_launch(void* const* d_in, const int* in_sizes, int n_in,
                              void* d_out, int out_size, void* d_ws, size_t ws_size,
                              hipStream_t stream) {
  const float* x     = (const float*)d_in[0];
  const int*   ei    = (const int*)d_in[1];
  const float* w_l0  = (const float*)d_in[2];
  const float* b_l0  = (const float*)d_in[3];
  const float* w_r0  = (const float*)d_in[4];
  const float* w_l1  = (const float*)d_in[5];
  const float* b_l1  = (const float*)d_in[6];
  const float* w_r1  = (const float*)d_in[7];
  const float* w_out = (const float*)d_in[8];
  const float* b_out = (const float*)d_in[9];
  float* out = (float*)d_out;

  const int* src = ei;
  const int* dst = ei + N_EDGES;

  char* ws = (char*)d_ws;
  int*      rowptr = (int*)(ws);                          // 400,004 B
  int*      gcur   = (int*)(ws + (512u << 10));           // 3,136 B
  int*      col    = (int*)(ws + (1u << 20));             // 6.4 MB (byte offsets)
  uint32_t* bdata  = (uint32_t*)(ws + (8u << 20));        // 8.03 MB (dead after k_csr)
  uint8_t*  x8     = (uint8_t*)(ws + (8u << 20));         // 12.8 MB (overlays bdata)
  uint8_t*  h08    = (uint8_t*)(ws + (8u << 20));         // 12.8 MB (overlays x8 after layer-0 agg)
  bf16*     WT0    = (bf16*)(ws + (21u << 20));           // 64 KB
  bf16*     WT1    = (bf16*)(ws + (21u << 20) + 65536);   // 64 KB
  bf16*     WoT    = (bf16*)(ws + (21u << 20) + 131072);  // 16 KB
  bf16*     aggb   = (bf16*)(ws + (22ull << 20));         // 25.6 MB
  bf16*     h0b    = (bf16*)(ws + (48ull << 20));         // 25.6 MB
  bf16*     xb     = (bf16*)(ws + (74ull << 20));         // 25.6 MB (~99.6 MB total)

  // --- CSR build first (bdata region is then reused for fp8 tables) ---
  hipMemsetAsync(gcur, 0, NREP * CB * sizeof(int), stream);
  k_bucket<<<(N_EDGES + EPB - 1) / EPB, 1024, 0, stream>>>(src, dst, gcur, bdata);
  k_csr   <<<CB, 256, 0, stream>>>(bdata, gcur, rowptr, col);

  // --- precompute (x -> bf16 + fp8; weights) ---
  k_cvt  <<<(N_NODES * DIM / 8 + 255) / 256, 256, 0, stream>>>(x, xb, x8);
  k_prepw<<<(65536 + 8192 + 255) / 256, 256, 0, stream>>>(w_l0, w_r0, w_l1, w_r1, w_out,
                                                          WT0, WT1, WoT);

  const int ablocks = (N_NODES * 64 + 255) / 256;
  const int gblocks = (N_NODES + NPB - 1) / NPB;

  // --- layer 0 ---
  k_agg <<<ablocks, 256, 0, stream>>>(x8, rowptr, col, aggb);
  k_sage<<<gblocks, 256, 0, stream>>>(aggb, xb, WT0, b_l0, h0b, h08);

  // --- layer 1 + head ---
  k_agg<<<ablocks, 256, 0, stream>>>(h08, rowptr, col, aggb);
  k_out<<<gblocks, 256, 0, stream>>>(aggb, h0b, WT1, b_l1, WoT, b_out, out);
}